// Round 8
// baseline (149.167 us; speedup 1.0000x reference)
//
#include <hip/hip_runtime.h>
#include <hip/hip_bf16.h>
#include <math.h>

namespace {

constexpr int L   = 64;    // steps
constexpr int NH  = 256;   // nhid
constexpr int NC  = 64;    // cache_N
constexpr int BSZ = 32;

typedef float f32x16 __attribute__((ext_vector_type(16)));
typedef short bf16x8 __attribute__((ext_vector_type(8)));   // 8 bf16 in 4 VGPRs

// Split 8 fp32 into hi/lo bf16x8: x = hi + lo + O(2^-18 x). (validated R3-R7)
__device__ inline void split8(const float4 x0, const float4 x1,
                              bf16x8& hi, bf16x8& lo) {
  float f[8];
  *(float4*)(f)     = x0;
  *(float4*)(f + 4) = x1;
#pragma unroll
  for (int q = 0; q < 8; ++q) {
    const __hip_bfloat16 h = __float2bfloat16(f[q]);        // RNE
    unsigned short hu;
    __builtin_memcpy(&hu, &h, 2);
    const float hf = __builtin_bit_cast(float, (unsigned)hu << 16);
    const __hip_bfloat16 l = __float2bfloat16(f[q] - hf);   // exact residual, RNE
    unsigned short lu;
    __builtin_memcpy(&lu, &l, 2);
    hi[q] = (short)hu;
    lo[q] = (short)lu;
  }
}

// global -> LDS direct: per-lane 16B, dest = uniform base + lane*16 (linear)
__device__ inline void gl16(const void* g, void* l) {
  __builtin_amdgcn_global_load_lds(
      (const __attribute__((address_space(1))) unsigned*)(g),
      (__attribute__((address_space(3))) unsigned*)(l), 16, 0, 0);
}

// ws layout: [0,4) completion counter | [4096, 4096+2MB) Q frag images (64KB/b)
// Frag image b: [0,32K) hi slots, [32K,64K) lo; slot s holds frag for
// it=s>>10, kc=(s>>6)&15, lane=s&63 (row it*32+(lane&31), k=kc*16+(lane>>5)*8).
__global__ __launch_bounds__(256) void qsplit_kernel(
    const float* __restrict__ query, char* __restrict__ ws) {
  if (blockIdx.x == 0 && threadIdx.x == 0) *(unsigned*)ws = 0u;  // ticket reset
  const int b   = blockIdx.x;
  const int tid = threadIdx.x;
  char* wb = ws + 4096 + (size_t)b * 65536;
#pragma unroll
  for (int rr = 0; rr < 8; ++rr) {
    const int s  = tid + rr * 256;          // 0..2047
    const int it = s >> 10;
    const int kc = (s >> 6) & 15;
    const int sl = s & 63;
    const int row = it * 32 + (sl & 31);
    const int kof = kc * 16 + (sl >> 5) * 8;
    const float* src = query + ((size_t)row * BSZ + b) * NH + kof;
    bf16x8 hi, lo;
    split8(*(const float4*)src, *(const float4*)(src + 4), hi, lo);
    *(bf16x8*)(wb + (size_t)s * 16)         = hi;
    *(bf16x8*)(wb + 32768 + (size_t)s * 16) = lo;
  }
}

// Block = 512 thr = 8 waves, owns (b, 4 n); wave w: (n = ng*4+(w>>1), jt=w&1),
// C strip 64x32. Q frags DMA'd from ws to LDS; K register-direct, depth-3
// rotating pipeline (static buffer names). Last block (device ticket) also
// computes the top-k indices inline — single fused pass, no extra kernel.
__global__ __launch_bounds__(512, 4) void attmax_mfma(
    const float* __restrict__ keys,    // (64, 32, 16384)
    char* __restrict__ ws,
    float* __restrict__ out)           // [0,2048) att ; [2048,2304) idx
{
  __shared__ __align__(16) char qlds[64 * 1024];  // hi [0,32K), lo [32K,64K)
  __shared__ float wm[8];
  __shared__ int lastFlag;
  const short* Qhi = (const short*)qlds;
  const short* Qlo = (const short*)(qlds + 32768);

  // grid 512: X = ng*32 + b  -> same-b blocks share XCD (X%8 == b%8)
  const unsigned X = blockIdx.x;
  const int b  = X & 31;
  const int ng = X >> 5;

  const int tid  = threadIdx.x;
  const int w    = tid >> 6;          // wave 0..7
  const int lane = tid & 63;
  const int n    = ng * 4 + (w >> 1);
  const int jt   = w & 1;

  // ---- DMA Q frag image (64KB) from ws: 8 rounds x 8 waves x 1KB ----
  {
    const char* src = ws + 4096 + (size_t)b * 65536;
#pragma unroll
    for (int q = 0; q < 8; ++q) {
      const int off = (q * 8 + w) * 1024;
      gl16(src + off + lane * 16, qlds + off);
    }
  }
  __syncthreads();   // drains the lds-DMA

  // ---- Main loop: depth-3 rotating register pipeline ----
  const float* kp = keys + ((size_t)n * BSZ + b) * (size_t)(L * NH)
                  + (size_t)(jt * 32 + (lane & 31)) * NH + (lane >> 5) * 8;

  f32x16 acc[2];
#pragma unroll
  for (int it = 0; it < 2; ++it)
#pragma unroll
    for (int e = 0; e < 16; ++e) acc[it][e] = 0.f;

  float4 K0[2], K1[2], K2[2];

#define LOAD_K(B, kc)                                    \
  do {                                                   \
    const float* p0 = kp + (kc) * 16;                    \
    (B)[0] = *(const float4*)(p0);                       \
    (B)[1] = *(const float4*)(p0 + 4);                   \
  } while (0)

#define COMPUTE(B, kc)                                                        \
  do {                                                                        \
    bf16x8 bh, bl;                                                            \
    split8((B)[0], (B)[1], bh, bl);                                           \
    _Pragma("unroll")                                                         \
    for (int it = 0; it < 2; ++it) {                                          \
      const int slot = ((it * 16 + (kc)) * 64 + lane) * 8;                    \
      const bf16x8 ah = *(const bf16x8*)&Qhi[slot];                           \
      const bf16x8 al = *(const bf16x8*)&Qlo[slot];                           \
      acc[it] = __builtin_amdgcn_mfma_f32_32x32x16_bf16(al, bh, acc[it], 0, 0, 0); \
      acc[it] = __builtin_amdgcn_mfma_f32_32x32x16_bf16(ah, bl, acc[it], 0, 0, 0); \
      acc[it] = __builtin_amdgcn_mfma_f32_32x32x16_bf16(ah, bh, acc[it], 0, 0, 0); \
    }                                                                         \
  } while (0)

#define STEP(B, kc, kn)                                  \
  do {                                                   \
    COMPUTE(B, kc);                                      \
    if ((kn) < 16) LOAD_K(B, kn);                        \
  } while (0)

  LOAD_K(K0, 0); LOAD_K(K1, 1); LOAD_K(K2, 2);
  STEP(K0, 0, 3);   STEP(K1, 1, 4);   STEP(K2, 2, 5);
  STEP(K0, 3, 6);   STEP(K1, 4, 7);   STEP(K2, 5, 8);
  STEP(K0, 6, 9);   STEP(K1, 7, 10);  STEP(K2, 8, 11);
  STEP(K0, 9, 12);  STEP(K1, 10, 13); STEP(K2, 11, 14);
  STEP(K0, 12, 15); STEP(K1, 13, 16); STEP(K2, 14, 17);
  STEP(K0, 15, 18);
#undef LOAD_K
#undef COMPUTE
#undef STEP

  // ---- Reduce: wave max, pair jt-waves, store att ----
  float m = -INFINITY;
#pragma unroll
  for (int it = 0; it < 2; ++it)
#pragma unroll
    for (int e = 0; e < 16; ++e) m = fmaxf(m, acc[it][e]);
#pragma unroll
  for (int off = 1; off < 64; off <<= 1)
    m = fmaxf(m, __shfl_xor(m, off, 64));

  if (lane == 0) wm[w] = m;
  __syncthreads();
  if (lane == 0 && (w & 1) == 0)
    out[(size_t)b * NC + n] = fmaxf(wm[w], wm[w + 1]);

  // ---- Last-block ticket: fused top-k (lowest-index tie-break) ----
  __threadfence();                       // release att stores
  if (tid == 0) {
    const unsigned t = atomicAdd((unsigned*)ws, 1u);
    lastFlag = (t == gridDim.x - 1);
  }
  __syncthreads();
  if (lastFlag) {
    __threadfence();                     // acquire all blocks' att stores
    if (tid < BSZ) {
      const int bb = tid;
      unsigned long long sel = 0ull;
      for (int k = 0; k < 8; ++k) {
        float best = -INFINITY;
        int bi = 0;
        for (int j = 0; j < 64; ++j) {
          if ((sel >> j) & 1ull) continue;
          const float v = out[bb * NC + j];
          if (v > best) { best = v; bi = j; }   // strict >: lowest idx on ties
        }
        sel |= 1ull << bi;
        out[BSZ * NC + k * BSZ + bb] = (float)bi;  // (topk, bsz) layout
      }
    }
  }
}

}  // namespace

extern "C" void kernel_launch(void* const* d_in, const int* in_sizes, int n_in,
                              void* d_out, int out_size, void* d_ws, size_t ws_size,
                              hipStream_t stream) {
  const float* query = (const float*)d_in[0];
  const float* keys  = (const float*)d_in[1];
  // d_in[2] (values) is dead code in the max_pooling branch — never read.
  float* out = (float*)d_out;
  char*  ws  = (char*)d_ws;   // [ticket counter | Q frag images]

  qsplit_kernel<<<dim3(BSZ), dim3(256), 0, stream>>>(query, ws);
  attmax_mfma<<<dim3(512), dim3(512), 0, stream>>>(keys, ws, out);
}

// Round 9
// 127.470 us; speedup vs baseline: 1.1702x; 1.1702x over previous
//
#include <hip/hip_runtime.h>
#include <hip/hip_bf16.h>
#include <math.h>

namespace {

constexpr int L   = 64;    // steps
constexpr int NH  = 256;   // nhid
constexpr int NC  = 64;    // cache_N
constexpr int BSZ = 32;

typedef float f32x16 __attribute__((ext_vector_type(16)));
typedef short bf16x8 __attribute__((ext_vector_type(8)));   // 8 bf16 in 4 VGPRs

// Split 8 fp32 into hi/lo bf16x8: x = hi + lo + O(2^-18 x). (validated R3-R8)
__device__ inline void split8(const float4 x0, const float4 x1,
                              bf16x8& hi, bf16x8& lo) {
  float f[8];
  *(float4*)(f)     = x0;
  *(float4*)(f + 4) = x1;
#pragma unroll
  for (int q = 0; q < 8; ++q) {
    const __hip_bfloat16 h = __float2bfloat16(f[q]);        // RNE
    unsigned short hu;
    __builtin_memcpy(&hu, &h, 2);
    const float hf = __builtin_bit_cast(float, (unsigned)hu << 16);
    const __hip_bfloat16 l = __float2bfloat16(f[q] - hf);   // exact residual, RNE
    unsigned short lu;
    __builtin_memcpy(&lu, &l, 2);
    hi[q] = (short)hu;
    lo[q] = (short)lu;
  }
}

// global -> LDS direct: per-lane 16B, dest = uniform base + lane*16 (linear)
__device__ inline void gl16(const void* g, void* l) {
  __builtin_amdgcn_global_load_lds(
      (const __attribute__((address_space(1))) unsigned*)(g),
      (__attribute__((address_space(3))) unsigned*)(l), 16, 0, 0);
}

// ws layout: [0,4) ticket counter | [4096, 4096+2MB) Q frag images (64KB/b).
// Frag image b: [0,32K) hi slots, [32K,64K) lo; slot s holds frag for
// it=s>>10, kc=(s>>6)&15, lane=s&63 (row it*32+(lane&31), k=kc*16+(lane>>5)*8).
__global__ __launch_bounds__(256) void qsplit_kernel(
    const float* __restrict__ query, char* __restrict__ ws) {
  if (blockIdx.x == 0 && threadIdx.x == 0) *(unsigned*)ws = 0u;  // ticket reset
  const int b   = blockIdx.x;
  const int tid = threadIdx.x;
  char* wb = ws + 4096 + (size_t)b * 65536;
#pragma unroll
  for (int rr = 0; rr < 8; ++rr) {
    const int s  = tid + rr * 256;          // 0..2047
    const int it = s >> 10;
    const int kc = (s >> 6) & 15;
    const int sl = s & 63;
    const int row = it * 32 + (sl & 31);
    const int kof = kc * 16 + (sl >> 5) * 8;
    const float* src = query + ((size_t)row * BSZ + b) * NH + kof;
    bf16x8 hi, lo;
    split8(*(const float4*)src, *(const float4*)(src + 4), hi, lo);
    *(bf16x8*)(wb + (size_t)s * 16)         = hi;
    *(bf16x8*)(wb + 32768 + (size_t)s * 16) = lo;
  }
}

// Block = 512 thr = 8 waves, owns (b, 4 n); wave w: (n = ng*4+(w>>1), jt=w&1),
// C strip 64x32. Q frags DMA'd from ws to LDS; K register-direct, depth-3
// rotating pipeline. Last block (device ticket) runs the wave-PARALLEL top-k
// (one value per lane + shuffle argmax), not a serial scan (R8's mistake).
__global__ __launch_bounds__(512, 4) void attmax_mfma(
    const float* __restrict__ keys,    // (64, 32, 16384)
    char* __restrict__ ws,
    float* __restrict__ out)           // [0,2048) att ; [2048,2304) idx
{
  __shared__ __align__(16) char qlds[64 * 1024];  // hi [0,32K), lo [32K,64K)
  __shared__ float wm[8];
  __shared__ int lastFlag;
  const short* Qhi = (const short*)qlds;
  const short* Qlo = (const short*)(qlds + 32768);

  // grid 512: X = ng*32 + b  -> same-b blocks share XCD (X%8 == b%8)
  const unsigned X = blockIdx.x;
  const int b  = X & 31;
  const int ng = X >> 5;

  const int tid  = threadIdx.x;
  const int w    = tid >> 6;          // wave 0..7
  const int lane = tid & 63;
  const int n    = ng * 4 + (w >> 1);
  const int jt   = w & 1;

  // ---- DMA Q frag image (64KB) from ws: 8 rounds x 8 waves x 1KB ----
  {
    const char* src = ws + 4096 + (size_t)b * 65536;
#pragma unroll
    for (int q = 0; q < 8; ++q) {
      const int off = (q * 8 + w) * 1024;
      gl16(src + off + lane * 16, qlds + off);
    }
  }
  __syncthreads();   // drains the lds-DMA

  // ---- Main loop: depth-3 rotating register pipeline ----
  const float* kp = keys + ((size_t)n * BSZ + b) * (size_t)(L * NH)
                  + (size_t)(jt * 32 + (lane & 31)) * NH + (lane >> 5) * 8;

  f32x16 acc[2];
#pragma unroll
  for (int it = 0; it < 2; ++it)
#pragma unroll
    for (int e = 0; e < 16; ++e) acc[it][e] = 0.f;

  float4 K0[2], K1[2], K2[2];

#define LOAD_K(B, kc)                                    \
  do {                                                   \
    const float* p0 = kp + (kc) * 16;                    \
    (B)[0] = *(const float4*)(p0);                       \
    (B)[1] = *(const float4*)(p0 + 4);                   \
  } while (0)

#define COMPUTE(B, kc)                                                        \
  do {                                                                        \
    bf16x8 bh, bl;                                                            \
    split8((B)[0], (B)[1], bh, bl);                                           \
    _Pragma("unroll")                                                         \
    for (int it = 0; it < 2; ++it) {                                          \
      const int slot = ((it * 16 + (kc)) * 64 + lane) * 8;                    \
      const bf16x8 ah = *(const bf16x8*)&Qhi[slot];                           \
      const bf16x8 al = *(const bf16x8*)&Qlo[slot];                           \
      acc[it] = __builtin_amdgcn_mfma_f32_32x32x16_bf16(al, bh, acc[it], 0, 0, 0); \
      acc[it] = __builtin_amdgcn_mfma_f32_32x32x16_bf16(ah, bl, acc[it], 0, 0, 0); \
      acc[it] = __builtin_amdgcn_mfma_f32_32x32x16_bf16(ah, bh, acc[it], 0, 0, 0); \
    }                                                                         \
  } while (0)

#define STEP(B, kc, kn)                                  \
  do {                                                   \
    COMPUTE(B, kc);                                      \
    if ((kn) < 16) LOAD_K(B, kn);                        \
  } while (0)

  LOAD_K(K0, 0); LOAD_K(K1, 1); LOAD_K(K2, 2);
  STEP(K0, 0, 3);   STEP(K1, 1, 4);   STEP(K2, 2, 5);
  STEP(K0, 3, 6);   STEP(K1, 4, 7);   STEP(K2, 5, 8);
  STEP(K0, 6, 9);   STEP(K1, 7, 10);  STEP(K2, 8, 11);
  STEP(K0, 9, 12);  STEP(K1, 10, 13); STEP(K2, 11, 14);
  STEP(K0, 12, 15); STEP(K1, 13, 16); STEP(K2, 14, 17);
  STEP(K0, 15, 18);
#undef LOAD_K
#undef COMPUTE
#undef STEP

  // ---- Reduce: wave max, pair jt-waves, store att ----
  float m = -INFINITY;
#pragma unroll
  for (int it = 0; it < 2; ++it)
#pragma unroll
    for (int e = 0; e < 16; ++e) m = fmaxf(m, acc[it][e]);
#pragma unroll
  for (int off = 1; off < 64; off <<= 1)
    m = fmaxf(m, __shfl_xor(m, off, 64));

  if (lane == 0) wm[w] = m;
  __syncthreads();
  if (lane == 0 && (w & 1) == 0)
    out[(size_t)b * NC + n] = fmaxf(wm[w], wm[w + 1]);

  // ---- Last-block ticket: wave-parallel fused top-k ----
  __threadfence();                       // release att stores
  if (tid == 0) {
    const unsigned t = atomicAdd((unsigned*)ws, 1u);
    lastFlag = (t == gridDim.x - 1);
  }
  __syncthreads();
  if (lastFlag) {
    __threadfence();                     // acquire all blocks' att stores
    // wave w handles batches w, w+8, w+16, w+24; lane l holds att[bb, l]
#pragma unroll
    for (int rep = 0; rep < 4; ++rep) {
      const int bb = rep * 8 + w;
      float v = out[bb * NC + lane];
#pragma unroll
      for (int k = 0; k < 8; ++k) {
        float bv = v;
        int bi = lane;
#pragma unroll
        for (int off = 1; off < 64; off <<= 1) {
          const float ov = __shfl_xor(bv, off, 64);
          const int oi = __shfl_xor(bi, off, 64);
          if (ov > bv || (ov == bv && oi < bi)) { bv = ov; bi = oi; }
        }
        if (lane == 0) out[BSZ * NC + k * BSZ + bb] = (float)bi;  // (topk,bsz)
        if (lane == bi) v = -INFINITY;
      }
    }
  }
}

}  // namespace

extern "C" void kernel_launch(void* const* d_in, const int* in_sizes, int n_in,
                              void* d_out, int out_size, void* d_ws, size_t ws_size,
                              hipStream_t stream) {
  const float* query = (const float*)d_in[0];
  const float* keys  = (const float*)d_in[1];
  // d_in[2] (values) is dead code in the max_pooling branch — never read.
  float* out = (float*)d_out;
  char*  ws  = (char*)d_ws;   // [ticket counter | Q frag images]

  qsplit_kernel<<<dim3(BSZ), dim3(256), 0, stream>>>(query, ws);
  attmax_mfma<<<dim3(512), dim3(512), 0, stream>>>(keys, ws, out);
}

// Round 10
// 40.912 us; speedup vs baseline: 3.6461x; 3.1157x over previous
//
#include <hip/hip_runtime.h>
#include <hip/hip_bf16.h>
#include <math.h>

namespace {

constexpr int L   = 64;    // steps
constexpr int NH  = 256;   // nhid
constexpr int NC  = 64;    // cache_N
constexpr int BSZ = 32;

typedef float f32x16 __attribute__((ext_vector_type(16)));
typedef short bf16x8 __attribute__((ext_vector_type(8)));   // 8 bf16 in 4 VGPRs

// Split 8 fp32 into hi/lo bf16x8: x = hi + lo + O(2^-18 x). (validated R3-R9)
__device__ inline void split8(const float4 x0, const float4 x1,
                              bf16x8& hi, bf16x8& lo) {
  float f[8];
  *(float4*)(f)     = x0;
  *(float4*)(f + 4) = x1;
#pragma unroll
  for (int q = 0; q < 8; ++q) {
    const __hip_bfloat16 h = __float2bfloat16(f[q]);        // RNE
    unsigned short hu;
    __builtin_memcpy(&hu, &h, 2);
    const float hf = __builtin_bit_cast(float, (unsigned)hu << 16);
    const __hip_bfloat16 l = __float2bfloat16(f[q] - hf);   // exact residual, RNE
    unsigned short lu;
    __builtin_memcpy(&lu, &l, 2);
    hi[q] = (short)hu;
    lo[q] = (short)lu;
  }
}

// global -> LDS direct: per-lane 16B, dest = uniform base + lane*16 (linear)
__device__ inline void gl16(const void* g, void* l) {
  __builtin_amdgcn_global_load_lds(
      (const __attribute__((address_space(1))) unsigned*)(g),
      (__attribute__((address_space(3))) unsigned*)(l), 16, 0, 0);
}

// ws: [0, 2MB) Q frag images (64KB per b).
// Frag image b: [0,32K) hi slots, [32K,64K) lo; slot s holds frag for
// it=s>>10, kc=(s>>6)&15, lane=s&63 (row it*32+(lane&31), k=kc*16+(lane>>5)*8).
__global__ __launch_bounds__(256) void qsplit_kernel(
    const float* __restrict__ query, char* __restrict__ ws) {
  const int b   = blockIdx.x;
  const int tid = threadIdx.x;
  char* wb = ws + (size_t)b * 65536;
#pragma unroll
  for (int rr = 0; rr < 8; ++rr) {
    const int s  = tid + rr * 256;          // 0..2047
    const int it = s >> 10;
    const int kc = (s >> 6) & 15;
    const int sl = s & 63;
    const int row = it * 32 + (sl & 31);
    const int kof = kc * 16 + (sl >> 5) * 8;
    const float* src = query + ((size_t)row * BSZ + b) * NH + kof;
    bf16x8 hi, lo;
    split8(*(const float4*)src, *(const float4*)(src + 4), hi, lo);
    *(bf16x8*)(wb + (size_t)s * 16)         = hi;
    *(bf16x8*)(wb + 32768 + (size_t)s * 16) = lo;
  }
}

// Block = 512 thr = 8 waves, owns (b, 4 n); wave w: (n = ng*4+(w>>1), jt=w&1),
// C strip 64x32. Q frags DMA'd from ws to LDS. K register-direct with a
// paired-kc depth-2 pipeline: each slot loads TWO kc chunks (4 dwordx4),
// so up to 8 VMEM instr in flight per wave x 4 waves/SIMD (2x R7's MLP).
__global__ __launch_bounds__(512, 4) void attmax_mfma(
    const float* __restrict__ keys,    // (64, 32, 16384)
    const char* __restrict__ ws,
    float* __restrict__ out)           // out[b*64+n] = att
{
  __shared__ __align__(16) char qlds[64 * 1024];  // hi [0,32K), lo [32K,64K)
  __shared__ float wm[8];
  const short* Qhi = (const short*)qlds;
  const short* Qlo = (const short*)(qlds + 32768);

  // grid 512: X = ng*32 + b  -> same-b blocks share XCD (X%8 == b%8)
  const unsigned X = blockIdx.x;
  const int b  = X & 31;
  const int ng = X >> 5;

  const int tid  = threadIdx.x;
  const int w    = tid >> 6;          // wave 0..7
  const int lane = tid & 63;
  const int n    = ng * 4 + (w >> 1);
  const int jt   = w & 1;

  // ---- DMA Q frag image (64KB) from ws: 8 rounds x 8 waves x 1KB ----
  {
    const char* src = ws + (size_t)b * 65536;
#pragma unroll
    for (int q = 0; q < 8; ++q) {
      const int off = (q * 8 + w) * 1024;
      gl16(src + off + lane * 16, qlds + off);
    }
  }
  __syncthreads();   // drains the lds-DMA

  // ---- Main loop: paired-kc depth-2 rotating register pipeline ----
  const float* kp = keys + ((size_t)n * BSZ + b) * (size_t)(L * NH)
                  + (size_t)(jt * 32 + (lane & 31)) * NH + (lane >> 5) * 8;

  f32x16 acc[2];
#pragma unroll
  for (int it = 0; it < 2; ++it)
#pragma unroll
    for (int e = 0; e < 16; ++e) acc[it][e] = 0.f;

  float4 K0[4], K1[4];   // each: two kc chunks (2 float4 per chunk)

#define LOAD2(B, kc)                                     \
  do {                                                   \
    const float* p0 = kp + (kc) * 16;                    \
    (B)[0] = *(const float4*)(p0);                       \
    (B)[1] = *(const float4*)(p0 + 4);                   \
    const float* p1 = kp + ((kc) + 1) * 16;              \
    (B)[2] = *(const float4*)(p1);                       \
    (B)[3] = *(const float4*)(p1 + 4);                   \
  } while (0)

#define COMP1(x0, x1, kc)                                                     \
  do {                                                                        \
    bf16x8 bh, bl;                                                            \
    split8((x0), (x1), bh, bl);                                               \
    _Pragma("unroll")                                                         \
    for (int it = 0; it < 2; ++it) {                                          \
      const int slot = ((it * 16 + (kc)) * 64 + lane) * 8;                    \
      const bf16x8 ah = *(const bf16x8*)&Qhi[slot];                           \
      const bf16x8 al = *(const bf16x8*)&Qlo[slot];                           \
      acc[it] = __builtin_amdgcn_mfma_f32_32x32x16_bf16(al, bh, acc[it], 0, 0, 0); \
      acc[it] = __builtin_amdgcn_mfma_f32_32x32x16_bf16(ah, bl, acc[it], 0, 0, 0); \
      acc[it] = __builtin_amdgcn_mfma_f32_32x32x16_bf16(ah, bh, acc[it], 0, 0, 0); \
    }                                                                         \
  } while (0)

#define COMP2(B, kc)                                     \
  do {                                                   \
    COMP1((B)[0], (B)[1], (kc));                         \
    COMP1((B)[2], (B)[3], (kc) + 1);                     \
  } while (0)

  LOAD2(K0, 0); LOAD2(K1, 2);
  COMP2(K0, 0);  LOAD2(K0, 4);
  COMP2(K1, 2);  LOAD2(K1, 6);
  COMP2(K0, 4);  LOAD2(K0, 8);
  COMP2(K1, 6);  LOAD2(K1, 10);
  COMP2(K0, 8);  LOAD2(K0, 12);
  COMP2(K1, 10); LOAD2(K1, 14);
  COMP2(K0, 12);
  COMP2(K1, 14);
#undef LOAD2
#undef COMP1
#undef COMP2

  // ---- Reduce: wave max, pair jt-waves, store att ----
  float m = -INFINITY;
#pragma unroll
  for (int it = 0; it < 2; ++it)
#pragma unroll
    for (int e = 0; e < 16; ++e) m = fmaxf(m, acc[it][e]);
#pragma unroll
  for (int off = 1; off < 64; off <<= 1)
    m = fmaxf(m, __shfl_xor(m, off, 64));

  if (lane == 0) wm[w] = m;
  __syncthreads();
  if (lane == 0 && (w & 1) == 0)
    out[(size_t)b * NC + n] = fmaxf(wm[w], wm[w + 1]);
}

// One block (64 lanes) per batch b: 8 rounds of argmax with lowest-index
// tie-break (matches jax.lax.top_k stability). Indices written as floats.
__global__ __launch_bounds__(64) void topk_kernel(float* __restrict__ out) {
  const int b = blockIdx.x;
  const int l = threadIdx.x;
  float v = out[b * NC + l];
#pragma unroll
  for (int k = 0; k < 8; ++k) {
    float bv = v;
    int bi = l;
#pragma unroll
    for (int off = 1; off < 64; off <<= 1) {
      const float ov = __shfl_xor(bv, off, 64);
      const int oi = __shfl_xor(bi, off, 64);
      if (ov > bv || (ov == bv && oi < bi)) { bv = ov; bi = oi; }
    }
    if (l == 0) out[BSZ * NC + k * BSZ + b] = (float)bi;  // (topk, bsz) layout
    if (l == bi) v = -INFINITY;
  }
}

}  // namespace

extern "C" void kernel_launch(void* const* d_in, const int* in_sizes, int n_in,
                              void* d_out, int out_size, void* d_ws, size_t ws_size,
                              hipStream_t stream) {
  const float* query = (const float*)d_in[0];
  const float* keys  = (const float*)d_in[1];
  // d_in[2] (values) is dead code in the max_pooling branch — never read.
  float* out = (float*)d_out;
  char*  ws  = (char*)d_ws;   // 2 MB Q frag images

  qsplit_kernel<<<dim3(BSZ), dim3(256), 0, stream>>>(query, ws);
  attmax_mfma<<<dim3(512), dim3(512), 0, stream>>>(keys, ws, out);
  topk_kernel<<<dim3(BSZ), dim3(64), 0, stream>>>(out);
}

// Round 11
// 40.821 us; speedup vs baseline: 3.6542x; 1.0022x over previous
//
#include <hip/hip_runtime.h>
#include <hip/hip_bf16.h>
#include <math.h>

namespace {

constexpr int L   = 64;    // steps
constexpr int NH  = 256;   // nhid
constexpr int NC  = 64;    // cache_N
constexpr int BSZ = 32;

typedef float f32x4 __attribute__((ext_vector_type(4)));
typedef short bf16x8 __attribute__((ext_vector_type(8)));   // 8 bf16 in 4 VGPRs

// Split 8 fp32 into hi/lo bf16x8: x = hi + lo + O(2^-18 x). (validated R3-R10)
__device__ inline void split8(const float4 x0, const float4 x1,
                              bf16x8& hi, bf16x8& lo) {
  float f[8];
  *(float4*)(f)     = x0;
  *(float4*)(f + 4) = x1;
#pragma unroll
  for (int q = 0; q < 8; ++q) {
    const __hip_bfloat16 h = __float2bfloat16(f[q]);        // RNE
    unsigned short hu;
    __builtin_memcpy(&hu, &h, 2);
    const float hf = __builtin_bit_cast(float, (unsigned)hu << 16);
    const __hip_bfloat16 l = __float2bfloat16(f[q] - hf);   // exact residual, RNE
    unsigned short lu;
    __builtin_memcpy(&lu, &l, 2);
    hi[q] = (short)hu;
    lo[q] = (short)lu;
  }
}

// global -> LDS direct: per-lane 16B, dest = uniform base + lane*16 (linear)
__device__ inline void gl16(const void* g, void* l) {
  __builtin_amdgcn_global_load_lds(
      (const __attribute__((address_space(1))) unsigned*)(g),
      (__attribute__((address_space(3))) unsigned*)(l), 16, 0, 0);
}

// Fragment convention (16x16x32, shared by A and B):
//   lane l, elem i  ->  row = (tile)*16 + (l&15),
//                       k   = kc*32 + (i>>2)*16 + ((l>>4)&3)*4 + (i&3)
// This makes elems 0-3 / 4-7 each a contiguous float4, and the 4 lane-groups
// (l>>4) tile a full 64B line per row: global loads become 16 rows x 64B
// contiguous full-line runs per instruction (line touched exactly once).
// Any consistent (row,k) bijection is valid because only max(C) is consumed.

// ws: [0, 2MB) Q frag images (64KB per b): hi [0,32K), lo [32K,64K);
// slot s = (it*8 + kc)*64 + l  (it=0..3 row-tiles, kc=0..7 k-chunks of 32).
__global__ __launch_bounds__(256) void qsplit_kernel(
    const float* __restrict__ query, char* __restrict__ ws) {
  const int X = blockIdx.x;           // 256 blocks: b = X>>3, s-group = X&7
  const int b = X >> 3;
  const int s = (X & 7) * 256 + threadIdx.x;   // 0..2047
  const int it = s >> 9;
  const int kc = (s >> 6) & 7;
  const int l  = s & 63;
  const int row = it * 16 + (l & 15);
  const int col = kc * 32 + ((l >> 4) & 3) * 4;
  const float* src = query + ((size_t)row * BSZ + b) * NH + col;
  bf16x8 hi, lo;
  split8(*(const float4*)src, *(const float4*)(src + 16), hi, lo);
  char* wb = ws + (size_t)b * 65536;
  *(bf16x8*)(wb + (size_t)s * 16)         = hi;
  *(bf16x8*)(wb + 32768 + (size_t)s * 16) = lo;
}

// Block = 512 thr = 8 waves, owns (b, 4 n); wave w: (n = ng*4+(w>>1),
// jhalf = w&1) -> C strip 64 x 32 as 4x2 fragments of 16x16. Q frags DMA'd
// from ws to LDS; K register-direct, depth-2 pipeline, full-line loads.
__global__ __launch_bounds__(512, 4) void attmax_mfma(
    const float* __restrict__ keys,    // (64, 32, 16384)
    const char* __restrict__ ws,
    float* __restrict__ out)           // out[b*64+n] = att
{
  __shared__ __align__(16) char qlds[64 * 1024];  // hi [0,32K), lo [32K,64K)
  __shared__ float wm[8];
  const short* Qhi = (const short*)qlds;
  const short* Qlo = (const short*)(qlds + 32768);

  // grid 512: X = ng*32 + b  -> same-b blocks share XCD (X%8 == b%8)
  const unsigned X = blockIdx.x;
  const int b  = X & 31;
  const int ng = X >> 5;

  const int tid  = threadIdx.x;
  const int w    = tid >> 6;          // wave 0..7
  const int lane = tid & 63;
  const int n     = ng * 4 + (w >> 1);
  const int jhalf = w & 1;

  // ---- DMA Q frag image (64KB) from ws: 8 rounds x 8 waves x 1KB ----
  {
    const char* src = ws + (size_t)b * 65536;
#pragma unroll
    for (int q = 0; q < 8; ++q) {
      const int off = (q * 8 + w) * 1024;
      gl16(src + off + lane * 16, qlds + off);
    }
  }
  __syncthreads();   // drains the lds-DMA

  // ---- Main loop ----
  // wave's K rows: keys[(n*32+b)*16384 + (jhalf*32 + jt*16 + (l&15))*256 + k]
  const float* kb = keys + ((size_t)n * BSZ + b) * (size_t)(L * NH)
                  + (size_t)jhalf * 32 * NH;
  const int rl = lane & 15;
  const int cq = ((lane >> 4) & 3) * 4;
  const float* kp0 = kb + (size_t)rl * NH + cq;          // j-tile 0
  const float* kp1 = kb + (size_t)(16 + rl) * NH + cq;   // j-tile 1

  f32x4 acc[4][2];
#pragma unroll
  for (int it = 0; it < 4; ++it)
#pragma unroll
    for (int jt = 0; jt < 2; ++jt)
#pragma unroll
      for (int e = 0; e < 4; ++e) acc[it][jt][e] = 0.f;

  float4 K0[4], K1[4];   // [jt*2 + run]: per kc, per j-tile, two float4 runs

#define LOADC(B, kc)                                     \
  do {                                                   \
    const float* p = kp0 + (kc) * 32;                    \
    (B)[0] = *(const float4*)(p);                        \
    (B)[1] = *(const float4*)(p + 16);                   \
    const float* q = kp1 + (kc) * 32;                    \
    (B)[2] = *(const float4*)(q);                        \
    (B)[3] = *(const float4*)(q + 16);                   \
  } while (0)

#define COMPC(B, kc)                                                          \
  do {                                                                        \
    bf16x8 bh0, bl0, bh1, bl1;                                                \
    split8((B)[0], (B)[1], bh0, bl0);                                         \
    split8((B)[2], (B)[3], bh1, bl1);                                         \
    _Pragma("unroll")                                                         \
    for (int it = 0; it < 4; ++it) {                                          \
      const int slot = ((it * 8 + (kc)) * 64 + lane) * 8;                     \
      const bf16x8 ah = *(const bf16x8*)&Qhi[slot];                           \
      const bf16x8 al = *(const bf16x8*)&Qlo[slot];                           \
      acc[it][0] = __builtin_amdgcn_mfma_f32_16x16x32_bf16(al, bh0, acc[it][0], 0, 0, 0); \
      acc[it][0] = __builtin_amdgcn_mfma_f32_16x16x32_bf16(ah, bl0, acc[it][0], 0, 0, 0); \
      acc[it][0] = __builtin_amdgcn_mfma_f32_16x16x32_bf16(ah, bh0, acc[it][0], 0, 0, 0); \
      acc[it][1] = __builtin_amdgcn_mfma_f32_16x16x32_bf16(al, bh1, acc[it][1], 0, 0, 0); \
      acc[it][1] = __builtin_amdgcn_mfma_f32_16x16x32_bf16(ah, bl1, acc[it][1], 0, 0, 0); \
      acc[it][1] = __builtin_amdgcn_mfma_f32_16x16x32_bf16(ah, bh1, acc[it][1], 0, 0, 0); \
    }                                                                         \
  } while (0)

  LOADC(K0, 0); LOADC(K1, 1);
  COMPC(K0, 0); LOADC(K0, 2);
  COMPC(K1, 1); LOADC(K1, 3);
  COMPC(K0, 2); LOADC(K0, 4);
  COMPC(K1, 3); LOADC(K1, 5);
  COMPC(K0, 4); LOADC(K0, 6);
  COMPC(K1, 5); LOADC(K1, 7);
  COMPC(K0, 6);
  COMPC(K1, 7);
#undef LOADC
#undef COMPC

  // ---- Reduce: wave max, pair the two jhalf-waves of each n ----
  float m = -INFINITY;
#pragma unroll
  for (int it = 0; it < 4; ++it)
#pragma unroll
    for (int jt = 0; jt < 2; ++jt)
#pragma unroll
      for (int e = 0; e < 4; ++e) m = fmaxf(m, acc[it][jt][e]);
#pragma unroll
  for (int off = 1; off < 64; off <<= 1)
    m = fmaxf(m, __shfl_xor(m, off, 64));

  if (lane == 0) wm[w] = m;
  __syncthreads();
  if (lane == 0 && (w & 1) == 0)
    out[(size_t)b * NC + n] = fmaxf(wm[w], wm[w + 1]);
}

// One block (64 lanes) per batch b: 8 rounds of argmax with lowest-index
// tie-break (matches jax.lax.top_k stability). Indices written as floats.
__global__ __launch_bounds__(64) void topk_kernel(float* __restrict__ out) {
  const int b = blockIdx.x;
  const int l = threadIdx.x;
  float v = out[b * NC + l];
#pragma unroll
  for (int k = 0; k < 8; ++k) {
    float bv = v;
    int bi = l;
#pragma unroll
    for (int off = 1; off < 64; off <<= 1) {
      const float ov = __shfl_xor(bv, off, 64);
      const int oi = __shfl_xor(bi, off, 64);
      if (ov > bv || (ov == bv && oi < bi)) { bv = ov; bi = oi; }
    }
    if (l == 0) out[BSZ * NC + k * BSZ + b] = (float)bi;  // (topk, bsz) layout
    if (l == bi) v = -INFINITY;
  }
}

}  // namespace

extern "C" void kernel_launch(void* const* d_in, const int* in_sizes, int n_in,
                              void* d_out, int out_size, void* d_ws, size_t ws_size,
                              hipStream_t stream) {
  const float* query = (const float*)d_in[0];
  const float* keys  = (const float*)d_in[1];
  // d_in[2] (values) is dead code in the max_pooling branch — never read.
  float* out = (float*)d_out;
  char*  ws  = (char*)d_ws;   // 2 MB Q frag images

  qsplit_kernel<<<dim3(256), dim3(256), 0, stream>>>(query, ws);
  attmax_mfma<<<dim3(512), dim3(512), 0, stream>>>(keys, ws, out);
  topk_kernel<<<dim3(BSZ), dim3(64), 0, stream>>>(out);
}